// Round 1
// baseline (1207.399 us; speedup 1.0000x reference)
//
#include <hip/hip_runtime.h>
#include <math.h>

// ---------------- constants ----------------
#define NTOT   33600      // 25600 + 6400 + 1600
#define NSEL   3000       // 3 levels x top-1000
#define CAND_CAP 8192
#define NWORDS 47         // ceil(3000/64)
#define ROWSTRIDE 48      // padded mask row stride (u64 words)

struct P21 {
  const float* feat[3];
  const float* Wobj[3];
  const float* bobj[3];
  const float* Wcls[3];
  const float* bcls[3];
  const float* Wreg[3];
  const float* breg[3];
};

// map (block, thread) -> (level, pixel-in-level, global index, dims)
__device__ __forceinline__ void level_of_block(int b, int t, int& l, int& p, int& g,
                                               int& HW, int& Wd, double& stride) {
  if (b < 100)      { l = 0; p = b * 256 + t;         g = p;          HW = 25600; Wd = 160; stride = 8.0;  }
  else if (b < 125) { l = 1; p = (b - 100) * 256 + t; g = 25600 + p;  HW = 6400;  Wd = 80;  stride = 16.0; }
  else              { l = 2; p = (b - 125) * 256 + t; g = 32000 + p;  HW = 1600;  Wd = 40;  stride = 32.0; }
}

__device__ __forceinline__ double sigmoid_d(double x) { return 1.0 / (1.0 + exp(-x)); }

__device__ __forceinline__ unsigned long long shfl64(unsigned long long v, int src) {
  unsigned lo = (unsigned)__shfl((int)(unsigned)(v & 0xFFFFFFFFull), src, 64);
  unsigned hi = (unsigned)__shfl((int)(unsigned)(v >> 32), src, 64);
  return (((unsigned long long)hi) << 32) | (unsigned long long)lo;
}

// ---------------- K1: 1x1 convs, score/label/box per pixel, score histogram ----------------
__global__ __launch_bounds__(256) void k_conv(P21 P,
    double* __restrict__ score_d, int* __restrict__ label_d,
    double* __restrict__ box_d, unsigned* __restrict__ hist) {
  int l, p, g, HW, Wd; double stride;
  level_of_block(blockIdx.x, threadIdx.x, l, p, g, HW, Wd, stride);
  if (p >= HW) return;

  const float* __restrict__ feat = P.feat[l];
  const float* __restrict__ Wobj = P.Wobj[l];
  const float* __restrict__ Wcls = P.Wcls[l];
  const float* __restrict__ Wreg = P.Wreg[l];
  const float* __restrict__ bcls = P.bcls[l];
  const float* fp = feat + p;

  double accO = (double)P.bobj[l][0];
  double accR[4];
#pragma unroll
  for (int j = 0; j < 4; j++) accR[j] = (double)P.breg[l][j];

  double maxv; int lab;
  {
    double a[16];
#pragma unroll
    for (int j = 0; j < 16; j++) a[j] = (double)bcls[j];
    for (int c = 0; c < 256; c++) {
      double xc = (double)fp[c * HW];
      accO = fma((double)Wobj[c], xc, accO);
#pragma unroll
      for (int j = 0; j < 4; j++) accR[j] = fma((double)Wreg[j * 256 + c], xc, accR[j]);
#pragma unroll
      for (int j = 0; j < 16; j++) a[j] = fma((double)Wcls[j * 256 + c], xc, a[j]);
    }
    maxv = a[0]; lab = 0;
#pragma unroll
    for (int j = 1; j < 16; j++) if (a[j] > maxv) { maxv = a[j]; lab = j; }
  }
  for (int ch = 1; ch < 5; ch++) {
    double a[16];
#pragma unroll
    for (int j = 0; j < 16; j++) a[j] = (double)bcls[ch * 16 + j];
    for (int c = 0; c < 256; c++) {
      double xc = (double)fp[c * HW];
#pragma unroll
      for (int j = 0; j < 16; j++) a[j] = fma((double)Wcls[(ch * 16 + j) * 256 + c], xc, a[j]);
    }
#pragma unroll
    for (int j = 0; j < 16; j++) if (a[j] > maxv) { maxv = a[j]; lab = ch * 16 + j; }
  }

  double score = sigmoid_d(accO) * sigmoid_d(maxv);
  int h = p / Wd, w = p - h * Wd;
  double ax = ((double)w + 0.5) * stride;
  double ay = ((double)h + 0.5) * stride;
  double e0 = exp(accR[0]) * stride;
  double e1 = exp(accR[1]) * stride;
  double e2 = exp(accR[2]) * stride;
  double e3 = exp(accR[3]) * stride;

  score_d[g] = score;
  label_d[g] = lab;
  box_d[4 * g + 0] = ax - e0;
  box_d[4 * g + 1] = ay - e1;
  box_d[4 * g + 2] = ax + e2;
  box_d[4 * g + 3] = ay + e3;

  unsigned key = __float_as_uint((float)score);   // score > 0 -> monotone key
  atomicAdd(&hist[l * 65536 + (key >> 16)], 1u);
}

// ---------------- K2a: find cutoff bin per level (count(bins >= B) >= 1000, count(bins > B) < 1000) ----------------
__global__ __launch_bounds__(256) void k_scan(const unsigned* __restrict__ hist,
                                              unsigned* __restrict__ cutB) {
  int l = blockIdx.x;
  const unsigned* h = hist + l * 65536;
  __shared__ unsigned cs[256];
  __shared__ unsigned hb[256];
  __shared__ int s_chunk;
  __shared__ unsigned s_acc;
  int t = threadIdx.x;
  unsigned s = 0;
  for (int b = 0; b < 256; b++) s += h[t * 256 + b];
  cs[t] = s;
  __syncthreads();
  if (t == 0) {
    unsigned acc = 0; int chunk = 0;
    for (int tt = 255; tt >= 0; tt--) {
      if (acc + cs[tt] >= 1000u) { chunk = tt; break; }
      acc += cs[tt];
    }
    s_chunk = chunk; s_acc = acc;
  }
  __syncthreads();
  int chunk = s_chunk;
  hb[t] = h[chunk * 256 + t];
  __syncthreads();
  if (t == 0) {
    unsigned acc = s_acc;
    unsigned B = (unsigned)(chunk * 256);
    for (int b = 255; b >= 0; b--) {
      unsigned c = hb[b];
      if (acc + c >= 1000u) { B = (unsigned)(chunk * 256 + b); break; }
      acc += c;
    }
    cutB[l] = B;
  }
}

// ---------------- K2b: compact candidates with key-bin >= cutoff ----------------
__global__ __launch_bounds__(256) void k_compact(const double* __restrict__ score_d,
    const unsigned* __restrict__ cutB, unsigned* __restrict__ cnt,
    double* __restrict__ cand_s, int* __restrict__ cand_g) {
  int l, p, g, HW, Wd; double stride;
  level_of_block(blockIdx.x, threadIdx.x, l, p, g, HW, Wd, stride);
  if (p >= HW) return;
  double sc = score_d[g];
  unsigned key = __float_as_uint((float)sc);
  if ((key >> 16) >= cutB[l]) {
    unsigned pos = atomicAdd(&cnt[l], 1u);
    if (pos < CAND_CAP) {
      cand_s[l * CAND_CAP + pos] = sc;
      cand_g[l * CAND_CAP + pos] = g;
    }
  }
}

// ---------------- K2c: exact rank among candidates; scatter top-1000 sorted ----------------
__global__ __launch_bounds__(256) void k_rank(const double* __restrict__ cand_s,
    const int* __restrict__ cand_g, const unsigned* __restrict__ cnt,
    const int* __restrict__ label_d, const double* __restrict__ box_d,
    double* __restrict__ sel_s, int* __restrict__ sel_lab, double* __restrict__ sel_box) {
  int idx = blockIdx.x * 256 + threadIdx.x;
  int l = idx / CAND_CAP;
  int q = idx - l * CAND_CAP;
  if (l >= 3) return;
  int M = (int)min(cnt[l], (unsigned)CAND_CAP);
  if (q >= M) return;
  double s = cand_s[l * CAND_CAP + q];
  int g = cand_g[l * CAND_CAP + q];
  int r = 0;
  for (int j = 0; j < M; j++) {
    double sj = cand_s[l * CAND_CAP + j];
    int gj = cand_g[l * CAND_CAP + j];
    r += (sj > s) || (sj == s && gj < g);   // desc by score, ties -> lower original index
  }
  if (r < 1000) {
    int o = l * 1000 + r;
    sel_s[o] = s;
    sel_lab[o] = label_d[g];
    sel_box[4 * o + 0] = box_d[4 * g + 0];
    sel_box[4 * o + 1] = box_d[4 * g + 1];
    sel_box[4 * o + 2] = box_d[4 * g + 2];
    sel_box[4 * o + 3] = box_d[4 * g + 3];
  }
}

// ---------------- K3a: stable argsort(-scores) over the 3000 by rank-counting ----------------
__global__ __launch_bounds__(256) void k_order(const double* __restrict__ sel_s,
                                               int* __restrict__ sortIdx) {
  int i = blockIdx.x * 256 + threadIdx.x;
  if (i >= NSEL) return;
  double s = sel_s[i];
  int r = 0;
  for (int j = 0; j < NSEL; j++) {
    double sj = sel_s[j];
    r += (sj > s) || (sj == s && j < i);
  }
  sortIdx[r] = i;
}

// ---------------- K3b: build sorted class-offset boxes + valid flags ----------------
__global__ __launch_bounds__(256) void k_build(const double* __restrict__ sel_s,
    const int* __restrict__ sel_lab, const double* __restrict__ sel_box,
    const int* __restrict__ sortIdx, double* __restrict__ sbox, int* __restrict__ svalid) {
  int r = blockIdx.x * 256 + threadIdx.x;
  if (r >= NSEL) return;
  int i = sortIdx[r];
  double off = (double)sel_lab[i] * 8192.0;
  sbox[4 * r + 0] = sel_box[4 * i + 0] + off;
  sbox[4 * r + 1] = sel_box[4 * i + 1] + off;
  sbox[4 * r + 2] = sel_box[4 * i + 2] + off;
  sbox[4 * r + 3] = sel_box[4 * i + 3] + off;
  svalid[r] = (sel_s[i] >= 0.05) ? 1 : 0;
}

// ---------------- K4: IoU suppression bitmask, row i suppresses j>i ----------------
__global__ __launch_bounds__(64) void k_mask(const double* __restrict__ sbox,
                                             unsigned long long* __restrict__ mask) {
  int i = blockIdx.x;
  int lane = threadIdx.x;
  double x1 = sbox[4 * i + 0], y1 = sbox[4 * i + 1];
  double x2 = sbox[4 * i + 2], y2 = sbox[4 * i + 3];
  double ar = (x2 - x1) * (y2 - y1);
  for (int w = 0; w < NWORDS; w++) {
    int j = w * 64 + lane;
    bool c = false;
    if (j < NSEL && j > i) {
      double bx1 = sbox[4 * j + 0], by1 = sbox[4 * j + 1];
      double bx2 = sbox[4 * j + 2], by2 = sbox[4 * j + 3];
      double arj = (bx2 - bx1) * (by2 - by1);
      double xx1 = fmax(x1, bx1), yy1 = fmax(y1, by1);
      double xx2 = fmin(x2, bx2), yy2 = fmin(y2, by2);
      double ww = fmax(1e-10, xx2 - xx1);
      double hh = fmax(1e-10, yy2 - yy1);
      double inter = ww * hh;
      double iou = inter / (ar + arj - inter + 1e-14);
      c = iou > 0.6;
    }
    unsigned long long word = __ballot(c);
    if (lane == 0) mask[(size_t)i * ROWSTRIDE + w] = word;
  }
}

// ---------------- K5: single-wave serial greedy scan with 8-deep row prefetch ----------------
__global__ __launch_bounds__(64) void k_nms_scan(const unsigned long long* __restrict__ mask,
    const int* __restrict__ svalid, const int* __restrict__ sortIdx,
    int* __restrict__ keepOrig) {
  int lane = threadIdx.x;
  unsigned long long removed = 0ull, validw = 0ull;
  if (lane < NWORDS) {
    for (int b = 0; b < 64; b++) {
      int j = lane * 64 + b;
      if (j < NSEL && svalid[j]) validw |= (1ull << b);
    }
  }
  unsigned long long buf[8];
#pragma unroll
  for (int d = 0; d < 8; d++)
    buf[d] = (lane < NWORDS) ? mask[(size_t)d * ROWSTRIDE + lane] : 0ull;

  for (int i0 = 0; i0 < NSEL; i0 += 8) {
#pragma unroll
    for (int d = 0; d < 8; d++) {
      int i = i0 + d;
      unsigned long long row = buf[d];
      int nf = i + 8;
      buf[d] = (nf < NSEL && lane < NWORDS) ? mask[(size_t)nf * ROWSTRIDE + lane] : 0ull;
      int wd = i >> 6, bt = i & 63;
      unsigned long long remw = shfl64(removed, wd);
      unsigned long long valw = shfl64(validw, wd);
      bool act = ((valw >> bt) & 1ull) && !((remw >> bt) & 1ull);
      if (act) removed |= row;   // act is wave-uniform
    }
  }
  if (lane < NWORDS) {
    unsigned long long keepw = validw & ~removed;
    for (int b = 0; b < 64; b++) {
      int j = lane * 64 + b;
      if (j < NSEL) keepOrig[sortIdx[j]] = (int)((keepw >> b) & 1ull);
    }
  }
}

// ---------------- K6: final outputs ----------------
__global__ __launch_bounds__(256) void k_out(const double* __restrict__ sel_s,
    const int* __restrict__ sel_lab, const double* __restrict__ sel_box,
    const int* __restrict__ keepOrig, float* __restrict__ out) {
  int i = blockIdx.x * 256 + threadIdx.x;
  if (i >= NSEL) return;
#pragma unroll
  for (int c = 0; c < 4; c++) {
    double v = sel_box[4 * i + c] / 1280.0;
    v = fmin(fmax(v, 0.0), 1.0);
    out[4 * i + c] = (float)v;
  }
  out[12000 + i] = (float)sel_s[i];
  out[15000 + i] = (float)sel_lab[i];
  out[18000 + i] = keepOrig[i] ? 1.0f : 0.0f;
}

// ---------------- launch ----------------
extern "C" void kernel_launch(void* const* d_in, const int* in_sizes, int n_in,
                              void* d_out, int out_size, void* d_ws, size_t ws_size,
                              hipStream_t stream) {
  P21 P;
  for (int l = 0; l < 3; l++) {
    P.feat[l] = (const float*)d_in[7 * l + 0];
    P.Wobj[l] = (const float*)d_in[7 * l + 1];
    P.bobj[l] = (const float*)d_in[7 * l + 2];
    P.Wcls[l] = (const float*)d_in[7 * l + 3];
    P.bcls[l] = (const float*)d_in[7 * l + 4];
    P.Wreg[l] = (const float*)d_in[7 * l + 5];
    P.breg[l] = (const float*)d_in[7 * l + 6];
  }

  char* ws = (char*)d_ws;
  size_t off = 0;
  auto alloc = [&](size_t bytes) -> char* {
    char* p = ws + off;
    off += (bytes + 15) & ~(size_t)15;
    return p;
  };
  double* score_d  = (double*)alloc((size_t)NTOT * 8);
  double* box_d    = (double*)alloc((size_t)NTOT * 4 * 8);
  int*    label_d  = (int*)   alloc((size_t)NTOT * 4);
  double* sel_s    = (double*)alloc((size_t)NSEL * 8);
  double* sel_box  = (double*)alloc((size_t)NSEL * 4 * 8);
  int*    sel_lab  = (int*)   alloc((size_t)NSEL * 4);
  int*    sortIdx  = (int*)   alloc((size_t)NSEL * 4);
  double* sbox     = (double*)alloc((size_t)NSEL * 4 * 8);
  int*    svalid   = (int*)   alloc((size_t)NSEL * 4);
  int*    keepOrig = (int*)   alloc((size_t)NSEL * 4);
  double* cand_s   = (double*)alloc((size_t)3 * CAND_CAP * 8);
  int*    cand_g   = (int*)   alloc((size_t)3 * CAND_CAP * 4);
  unsigned long long* mask = (unsigned long long*)alloc((size_t)NSEL * ROWSTRIDE * 8);
  unsigned* hist   = (unsigned*)alloc((size_t)3 * 65536 * 4);   // 786432, 16-aligned
  unsigned* cnt    = (unsigned*)alloc(16);                      // adjacent to hist
  unsigned* cutB   = (unsigned*)alloc(16);

  // zero histogram + candidate counters (ws is poisoned 0xAA before every launch)
  hipMemsetAsync(hist, 0, (size_t)3 * 65536 * 4 + 16, stream);

  k_conv   <<<132, 256, 0, stream>>>(P, score_d, label_d, box_d, hist);
  k_scan   <<<3, 256, 0, stream>>>(hist, cutB);
  k_compact<<<132, 256, 0, stream>>>(score_d, cutB, cnt, cand_s, cand_g);
  k_rank   <<<(3 * CAND_CAP) / 256, 256, 0, stream>>>(cand_s, cand_g, cnt, label_d, box_d,
                                                      sel_s, sel_lab, sel_box);
  k_order  <<<(NSEL + 255) / 256, 256, 0, stream>>>(sel_s, sortIdx);
  k_build  <<<(NSEL + 255) / 256, 256, 0, stream>>>(sel_s, sel_lab, sel_box, sortIdx, sbox, svalid);
  k_mask   <<<NSEL, 64, 0, stream>>>(sbox, mask);
  k_nms_scan<<<1, 64, 0, stream>>>(mask, svalid, sortIdx, keepOrig);
  k_out    <<<(NSEL + 255) / 256, 256, 0, stream>>>(sel_s, sel_lab, sel_box, keepOrig, (float*)d_out);
}

// Round 2
// 817.262 us; speedup vs baseline: 1.4774x; 1.4774x over previous
//
#include <hip/hip_runtime.h>
#include <math.h>

// ---------------- constants ----------------
#define NTOT   33600      // 25600 + 6400 + 1600
#define NSEL   3000       // 3 levels x top-1000
#define CAND_CAP 8192
#define NWORDS 47         // ceil(3000/64)
#define ROWSTRIDE 48      // padded mask row stride (u64 words)
#define PF 16             // nms scan prefetch depth

struct P21 {
  const float* feat[3];
  const float* Wobj[3];
  const float* bobj[3];
  const float* Wcls[3];
  const float* bcls[3];
  const float* Wreg[3];
  const float* breg[3];
};

// map (block, thread) -> (level, pixel-in-level, global index, dims)
__device__ __forceinline__ void level_of_block(int b, int t, int& l, int& p, int& g,
                                               int& HW, int& Wd, double& stride) {
  if (b < 100)      { l = 0; p = b * 256 + t;         g = p;          HW = 25600; Wd = 160; stride = 8.0;  }
  else if (b < 125) { l = 1; p = (b - 100) * 256 + t; g = 25600 + p;  HW = 6400;  Wd = 80;  stride = 16.0; }
  else              { l = 2; p = (b - 125) * 256 + t; g = 32000 + p;  HW = 1600;  Wd = 40;  stride = 32.0; }
}

__device__ __forceinline__ double sigmoid_d(double x) { return 1.0 / (1.0 + exp(-x)); }

__device__ __forceinline__ unsigned long long shfl64(unsigned long long v, int src) {
  unsigned lo = (unsigned)__shfl((int)(unsigned)(v & 0xFFFFFFFFull), src, 64);
  unsigned hi = (unsigned)__shfl((int)(unsigned)(v >> 32), src, 64);
  return (((unsigned long long)hi) << 32) | (unsigned long long)lo;
}

// ---------------- K1: 1x1 convs split into 6 chunks (grid.y) ----------------
// chunk 0: obj + 4 reg outputs.  chunk 1..5: classes [16*(chunk-1), +16).
// Accumulation order per output identical to a straight c=0..255 fma chain
// (unroll-by-8 keeps each accumulator's chain sequential) -> bit-exact.
__global__ __launch_bounds__(256) void k_conv_chunk(P21 P,
    double* __restrict__ obj_t, double* __restrict__ reg_t,
    double* __restrict__ cmax, int* __restrict__ clab) {
  int l, p, g, HW, Wd; double stride;
  level_of_block(blockIdx.x, threadIdx.x, l, p, g, HW, Wd, stride);
  if (p >= HW) return;
  const int chunk = blockIdx.y;
  const float* __restrict__ fp = P.feat[l] + p;

  if (chunk == 0) {
    const float* __restrict__ Wobj = P.Wobj[l];
    const float* __restrict__ Wreg = P.Wreg[l];
    double accO = (double)P.bobj[l][0];
    double accR[4];
#pragma unroll
    for (int j = 0; j < 4; j++) accR[j] = (double)P.breg[l][j];
    for (int c = 0; c < 256; c += 8) {
      double xc[8];
#pragma unroll
      for (int u = 0; u < 8; u++) xc[u] = (double)fp[(c + u) * HW];
#pragma unroll
      for (int u = 0; u < 8; u++) {
        accO = fma((double)Wobj[c + u], xc[u], accO);
#pragma unroll
        for (int j = 0; j < 4; j++)
          accR[j] = fma((double)Wreg[j * 256 + c + u], xc[u], accR[j]);
      }
    }
    obj_t[g] = accO;
#pragma unroll
    for (int j = 0; j < 4; j++) reg_t[4 * g + j] = accR[j];
  } else {
    const int base = (chunk - 1) * 16;
    const float* __restrict__ Wcls = P.Wcls[l];
    const float* __restrict__ bcls = P.bcls[l];
    double a[16];
#pragma unroll
    for (int j = 0; j < 16; j++) a[j] = (double)bcls[base + j];
    for (int c = 0; c < 256; c += 8) {
      double xc[8];
#pragma unroll
      for (int u = 0; u < 8; u++) xc[u] = (double)fp[(c + u) * HW];
#pragma unroll
      for (int u = 0; u < 8; u++) {
#pragma unroll
        for (int j = 0; j < 16; j++)
          a[j] = fma((double)Wcls[(base + j) * 256 + c + u], xc[u], a[j]);
      }
    }
    double maxv = a[0]; int lab = base;
#pragma unroll
    for (int j = 1; j < 16; j++) if (a[j] > maxv) { maxv = a[j]; lab = base + j; }
    cmax[(chunk - 1) * NTOT + g] = maxv;
    clab[(chunk - 1) * NTOT + g] = lab;
  }
}

// ---------------- K1b: combine chunks -> score/label/box + histogram ----------------
__global__ __launch_bounds__(256) void k_combine(
    const double* __restrict__ obj_t, const double* __restrict__ reg_t,
    const double* __restrict__ cmax, const int* __restrict__ clab,
    double* __restrict__ score_d, int* __restrict__ label_d,
    double* __restrict__ box_d, unsigned* __restrict__ hist) {
  int l, p, g, HW, Wd; double stride;
  level_of_block(blockIdx.x, threadIdx.x, l, p, g, HW, Wd, stride);
  if (p >= HW) return;

  double maxv = cmax[g]; int lab = clab[g];
#pragma unroll
  for (int k = 1; k < 5; k++) {
    double v = cmax[k * NTOT + g];
    int lb = clab[k * NTOT + g];
    if (v > maxv) { maxv = v; lab = lb; }   // strict > keeps earliest class on ties
  }
  double score = sigmoid_d(obj_t[g]) * sigmoid_d(maxv);
  int h = p / Wd, w = p - h * Wd;
  double ax = ((double)w + 0.5) * stride;
  double ay = ((double)h + 0.5) * stride;
  double e0 = exp(reg_t[4 * g + 0]) * stride;
  double e1 = exp(reg_t[4 * g + 1]) * stride;
  double e2 = exp(reg_t[4 * g + 2]) * stride;
  double e3 = exp(reg_t[4 * g + 3]) * stride;

  score_d[g] = score;
  label_d[g] = lab;
  box_d[4 * g + 0] = ax - e0;
  box_d[4 * g + 1] = ay - e1;
  box_d[4 * g + 2] = ax + e2;
  box_d[4 * g + 3] = ay + e3;

  unsigned key = __float_as_uint((float)score);   // score > 0 -> monotone key
  atomicAdd(&hist[l * 65536 + (key >> 16)], 1u);
}

// ---------------- K2a: find cutoff bin per level ----------------
__global__ __launch_bounds__(256) void k_scan(const unsigned* __restrict__ hist,
                                              unsigned* __restrict__ cutB) {
  int l = blockIdx.x;
  const unsigned* h = hist + l * 65536;
  __shared__ unsigned cs[256];
  __shared__ unsigned hb[256];
  __shared__ int s_chunk;
  __shared__ unsigned s_acc;
  int t = threadIdx.x;
  unsigned s = 0;
  for (int b = 0; b < 256; b++) s += h[t * 256 + b];
  cs[t] = s;
  __syncthreads();
  if (t == 0) {
    unsigned acc = 0; int chunk = 0;
    for (int tt = 255; tt >= 0; tt--) {
      if (acc + cs[tt] >= 1000u) { chunk = tt; break; }
      acc += cs[tt];
    }
    s_chunk = chunk; s_acc = acc;
  }
  __syncthreads();
  int chunk = s_chunk;
  hb[t] = h[chunk * 256 + t];
  __syncthreads();
  if (t == 0) {
    unsigned acc = s_acc;
    unsigned B = (unsigned)(chunk * 256);
    for (int b = 255; b >= 0; b--) {
      unsigned c = hb[b];
      if (acc + c >= 1000u) { B = (unsigned)(chunk * 256 + b); break; }
      acc += c;
    }
    cutB[l] = B;
  }
}

// ---------------- K2b: compact candidates with key-bin >= cutoff ----------------
__global__ __launch_bounds__(256) void k_compact(const double* __restrict__ score_d,
    const unsigned* __restrict__ cutB, unsigned* __restrict__ cnt,
    double* __restrict__ cand_s, int* __restrict__ cand_g) {
  int l, p, g, HW, Wd; double stride;
  level_of_block(blockIdx.x, threadIdx.x, l, p, g, HW, Wd, stride);
  if (p >= HW) return;
  double sc = score_d[g];
  unsigned key = __float_as_uint((float)sc);
  if ((key >> 16) >= cutB[l]) {
    unsigned pos = atomicAdd(&cnt[l], 1u);
    if (pos < CAND_CAP) {
      cand_s[l * CAND_CAP + pos] = sc;
      cand_g[l * CAND_CAP + pos] = g;
    }
  }
}

// ---------------- K2c: exact rank among candidates; scatter top-1000 sorted ----------------
__global__ __launch_bounds__(256) void k_rank(const double* __restrict__ cand_s,
    const int* __restrict__ cand_g, const unsigned* __restrict__ cnt,
    const int* __restrict__ label_d, const double* __restrict__ box_d,
    double* __restrict__ sel_s, int* __restrict__ sel_lab, double* __restrict__ sel_box) {
  int idx = blockIdx.x * 256 + threadIdx.x;
  int l = idx / CAND_CAP;
  int q = idx - l * CAND_CAP;
  if (l >= 3) return;
  int M = (int)min(cnt[l], (unsigned)CAND_CAP);
  if (q >= M) return;
  double s = cand_s[l * CAND_CAP + q];
  int g = cand_g[l * CAND_CAP + q];
  int r = 0;
  for (int j = 0; j < M; j++) {
    double sj = cand_s[l * CAND_CAP + j];
    int gj = cand_g[l * CAND_CAP + j];
    r += (sj > s) || (sj == s && gj < g);   // desc by score, ties -> lower original index
  }
  if (r < 1000) {
    int o = l * 1000 + r;
    sel_s[o] = s;
    sel_lab[o] = label_d[g];
    sel_box[4 * o + 0] = box_d[4 * g + 0];
    sel_box[4 * o + 1] = box_d[4 * g + 1];
    sel_box[4 * o + 2] = box_d[4 * g + 2];
    sel_box[4 * o + 3] = box_d[4 * g + 3];
  }
}

// ---------------- K3a: stable argsort(-scores) over the 3000 ----------------
__global__ __launch_bounds__(256) void k_order(const double* __restrict__ sel_s,
                                               int* __restrict__ sortIdx) {
  int i = blockIdx.x * 256 + threadIdx.x;
  if (i >= NSEL) return;
  double s = sel_s[i];
  int r = 0;
  for (int j = 0; j < NSEL; j++) {
    double sj = sel_s[j];
    r += (sj > s) || (sj == s && j < i);
  }
  sortIdx[r] = i;
}

// ---------------- K3b: build sorted class-offset boxes + valid flags ----------------
__global__ __launch_bounds__(256) void k_build(const double* __restrict__ sel_s,
    const int* __restrict__ sel_lab, const double* __restrict__ sel_box,
    const int* __restrict__ sortIdx, double* __restrict__ sbox, int* __restrict__ svalid) {
  int r = blockIdx.x * 256 + threadIdx.x;
  if (r >= NSEL) return;
  int i = sortIdx[r];
  double off = (double)sel_lab[i] * 8192.0;
  sbox[4 * r + 0] = sel_box[4 * i + 0] + off;
  sbox[4 * r + 1] = sel_box[4 * i + 1] + off;
  sbox[4 * r + 2] = sel_box[4 * i + 2] + off;
  sbox[4 * r + 3] = sel_box[4 * i + 3] + off;
  svalid[r] = (sel_s[i] >= 0.05) ? 1 : 0;
}

// ---------------- K4: IoU suppression bitmask + diagonal words ----------------
__global__ __launch_bounds__(64) void k_mask(const double* __restrict__ sbox,
                                             unsigned long long* __restrict__ mask,
                                             unsigned long long* __restrict__ diag) {
  int i = blockIdx.x;
  int lane = threadIdx.x;
  double x1 = sbox[4 * i + 0], y1 = sbox[4 * i + 1];
  double x2 = sbox[4 * i + 2], y2 = sbox[4 * i + 3];
  double ar = (x2 - x1) * (y2 - y1);
  int iw = i >> 6;
  for (int w = 0; w < NWORDS; w++) {
    int j = w * 64 + lane;
    bool c = false;
    if (j < NSEL && j > i) {
      double bx1 = sbox[4 * j + 0], by1 = sbox[4 * j + 1];
      double bx2 = sbox[4 * j + 2], by2 = sbox[4 * j + 3];
      double arj = (bx2 - bx1) * (by2 - by1);
      double xx1 = fmax(x1, bx1), yy1 = fmax(y1, by1);
      double xx2 = fmin(x2, bx2), yy2 = fmin(y2, by2);
      double ww = fmax(1e-10, xx2 - xx1);
      double hh = fmax(1e-10, yy2 - yy1);
      double inter = ww * hh;
      double iou = inter / (ar + arj - inter + 1e-14);
      c = iou > 0.6;
    }
    unsigned long long word = __ballot(c);
    if (lane == 0) {
      mask[(size_t)i * ROWSTRIDE + w] = word;
      if (w == iw) diag[i] = word;       // row i's bits within its own 64-block
    }
  }
}

// ---------------- K5: single-wave serial greedy scan ----------------
// Critical path per i: branchless 64-bit window update (no shuffles);
// shuffles only at 47 block transitions. 16-deep prefetch of row+diag words.
__global__ __launch_bounds__(64) void k_nms_scan(const unsigned long long* __restrict__ mask,
    const unsigned long long* __restrict__ diag,
    const int* __restrict__ svalid, const int* __restrict__ sortIdx,
    int* __restrict__ keepOrig) {
  int lane = threadIdx.x;
  unsigned long long removed = 0ull, validw = 0ull;
  if (lane < NWORDS) {
    for (int b = 0; b < 64; b++) {
      int j = lane * 64 + b;
      if (j < NSEL && svalid[j]) validw |= (1ull << b);
    }
  }
  unsigned long long bufr[PF], bufd[PF];
#pragma unroll
  for (int d = 0; d < PF; d++) {
    bufr[d] = (lane < NWORDS) ? mask[(size_t)d * ROWSTRIDE + lane] : 0ull;
    bufd[d] = diag[d];
  }
  unsigned long long win = 0ull;
  for (int i0 = 0; i0 < 3008; i0 += PF) {          // 47*64 = 3008, padded tail inactive
#pragma unroll
    for (int d = 0; d < PF; d++) {
      int i = i0 + d;
      unsigned long long row = bufr[d];
      unsigned long long dgi = bufd[d];
      int nf = i + PF;
      bufr[d] = (nf < NSEL && lane < NWORDS) ? mask[(size_t)nf * ROWSTRIDE + lane] : 0ull;
      bufd[d] = (nf < NSEL) ? diag[nf] : 0ull;
      int bt = i & 63, wd = i >> 6;
      if (bt == 0) win = shfl64(validw & ~removed, wd);   // uniform branch, 47x total
      unsigned long long act = (win >> bt) & 1ull;
      unsigned long long m = 0ull - act;                   // all-ones if active
      win &= ~(dgi & m);
      removed |= (row & m);
    }
  }
  if (lane < NWORDS) {
    unsigned long long keepw = validw & ~removed;
    for (int b = 0; b < 64; b++) {
      int j = lane * 64 + b;
      if (j < NSEL) keepOrig[sortIdx[j]] = (int)((keepw >> b) & 1ull);
    }
  }
}

// ---------------- K6: final outputs ----------------
__global__ __launch_bounds__(256) void k_out(const double* __restrict__ sel_s,
    const int* __restrict__ sel_lab, const double* __restrict__ sel_box,
    const int* __restrict__ keepOrig, float* __restrict__ out) {
  int i = blockIdx.x * 256 + threadIdx.x;
  if (i >= NSEL) return;
#pragma unroll
  for (int c = 0; c < 4; c++) {
    double v = sel_box[4 * i + c] / 1280.0;
    v = fmin(fmax(v, 0.0), 1.0);
    out[4 * i + c] = (float)v;
  }
  out[12000 + i] = (float)sel_s[i];
  out[15000 + i] = (float)sel_lab[i];
  out[18000 + i] = keepOrig[i] ? 1.0f : 0.0f;
}

// ---------------- launch ----------------
extern "C" void kernel_launch(void* const* d_in, const int* in_sizes, int n_in,
                              void* d_out, int out_size, void* d_ws, size_t ws_size,
                              hipStream_t stream) {
  P21 P;
  for (int l = 0; l < 3; l++) {
    P.feat[l] = (const float*)d_in[7 * l + 0];
    P.Wobj[l] = (const float*)d_in[7 * l + 1];
    P.bobj[l] = (const float*)d_in[7 * l + 2];
    P.Wcls[l] = (const float*)d_in[7 * l + 3];
    P.bcls[l] = (const float*)d_in[7 * l + 4];
    P.Wreg[l] = (const float*)d_in[7 * l + 5];
    P.breg[l] = (const float*)d_in[7 * l + 6];
  }

  char* ws = (char*)d_ws;
  size_t off = 0;
  auto alloc = [&](size_t bytes) -> char* {
    char* p = ws + off;
    off += (bytes + 15) & ~(size_t)15;
    return p;
  };
  double* score_d  = (double*)alloc((size_t)NTOT * 8);
  double* box_d    = (double*)alloc((size_t)NTOT * 4 * 8);
  int*    label_d  = (int*)   alloc((size_t)NTOT * 4);
  double* obj_t    = (double*)alloc((size_t)NTOT * 8);
  double* reg_t    = (double*)alloc((size_t)NTOT * 4 * 8);
  double* cmax     = (double*)alloc((size_t)5 * NTOT * 8);
  int*    clab     = (int*)   alloc((size_t)5 * NTOT * 4);
  double* sel_s    = (double*)alloc((size_t)NSEL * 8);
  double* sel_box  = (double*)alloc((size_t)NSEL * 4 * 8);
  int*    sel_lab  = (int*)   alloc((size_t)NSEL * 4);
  int*    sortIdx  = (int*)   alloc((size_t)NSEL * 4);
  double* sbox     = (double*)alloc((size_t)NSEL * 4 * 8);
  int*    svalid   = (int*)   alloc((size_t)NSEL * 4);
  int*    keepOrig = (int*)   alloc((size_t)NSEL * 4);
  double* cand_s   = (double*)alloc((size_t)3 * CAND_CAP * 8);
  int*    cand_g   = (int*)   alloc((size_t)3 * CAND_CAP * 4);
  unsigned long long* mask = (unsigned long long*)alloc((size_t)NSEL * ROWSTRIDE * 8);
  unsigned long long* diag = (unsigned long long*)alloc((size_t)NSEL * 8);
  unsigned* hist   = (unsigned*)alloc((size_t)3 * 65536 * 4);   // 786432, 16-aligned
  unsigned* cnt    = (unsigned*)alloc(16);                      // adjacent to hist
  unsigned* cutB   = (unsigned*)alloc(16);

  // zero histogram + candidate counters (ws is poisoned 0xAA before every launch)
  hipMemsetAsync(hist, 0, (size_t)3 * 65536 * 4 + 16, stream);

  dim3 cgrid(132, 6, 1);
  k_conv_chunk<<<cgrid, 256, 0, stream>>>(P, obj_t, reg_t, cmax, clab);
  k_combine <<<132, 256, 0, stream>>>(obj_t, reg_t, cmax, clab, score_d, label_d, box_d, hist);
  k_scan    <<<3, 256, 0, stream>>>(hist, cutB);
  k_compact <<<132, 256, 0, stream>>>(score_d, cutB, cnt, cand_s, cand_g);
  k_rank    <<<(3 * CAND_CAP) / 256, 256, 0, stream>>>(cand_s, cand_g, cnt, label_d, box_d,
                                                       sel_s, sel_lab, sel_box);
  k_order   <<<(NSEL + 255) / 256, 256, 0, stream>>>(sel_s, sortIdx);
  k_build   <<<(NSEL + 255) / 256, 256, 0, stream>>>(sel_s, sel_lab, sel_box, sortIdx, sbox, svalid);
  k_mask    <<<NSEL, 64, 0, stream>>>(sbox, mask, diag);
  k_nms_scan<<<1, 64, 0, stream>>>(mask, diag, svalid, sortIdx, keepOrig);
  k_out     <<<(NSEL + 255) / 256, 256, 0, stream>>>(sel_s, sel_lab, sel_box, keepOrig, (float*)d_out);
}